// Round 6
// baseline (1342.505 us; speedup 1.0000x reference)
//
#include <hip/hip_runtime.h>
#include <cstdint>
#include <cstddef>

#define BB 256
#define TT 250
#define DIN 700
#define H1 256
#define H2 256
#define DOUT 20
#define BJ0 0.01f
#define BETAC 1.8f
#define DUMMY 256                 // zero row index in every padded table

typedef float f32x4 __attribute__((ext_vector_type(4)));

// Workspace layout (floats). Each weight table has one extra ZERO row.
//   wT1  [701*256] @ 0
//   wT11 [257*256] @ 179456
//   wT12 [257*256] @ 245248
//   wT22 [257*256] @ 311040
//   wT2o [257*20 ] @ 376832
//   Xp   [250*256*256] @ 381972
#define OFF_WT11 179456
#define OFF_WT12 245248
#define OFF_WT22 311040
#define OFF_WT2O 376832
#define OFF_XP   381972
#define N_TRANS  381972

__global__ void transpose_all_k(const float* __restrict__ w_i2h1,
                                const float* __restrict__ w_h12h1,
                                const float* __restrict__ w_h12h2,
                                const float* __restrict__ w_h22h2,
                                const float* __restrict__ w_h2o,
                                float* __restrict__ ws) {
    int i = blockIdx.x * blockDim.x + threadIdx.x;
    if (i < 179456) { int d = i >> 8, h = i & 255;
        ws[i] = (d < DIN) ? w_i2h1[h * DIN + d] : 0.f; return; }
    i -= 179456;
    if (i < 65792) { int d = i >> 8, h = i & 255;
        ws[OFF_WT11 + i] = (d < H1) ? w_h12h1[h * H1 + d] : 0.f; return; }
    i -= 65792;
    if (i < 65792) { int d = i >> 8, h = i & 255;
        ws[OFF_WT12 + i] = (d < H1) ? w_h12h2[h * H1 + d] : 0.f; return; }
    i -= 65792;
    if (i < 65792) { int d = i >> 8, h = i & 255;
        ws[OFF_WT22 + i] = (d < H2) ? w_h22h2[h * H2 + d] : 0.f; return; }
    i -= 65792;
    if (i < 5140)  { int j = i / 20, h = i % 20;
        ws[OFF_WT2O + i] = (j < H2) ? w_h2o[h * H2 + j] : 0.f; return; }
}

// ---------------------------------------------------------------------------
// Xp[t][b][h] = b_h1[h] + sum_{d active} wT1[d*256 + h]
// One wave per (b,t); lane covers h=4l..4l+3 via float4; 8 loads in flight.
// ---------------------------------------------------------------------------
__global__ __launch_bounds__(256) void xproj_k(const float* __restrict__ x,
                                               const float* __restrict__ wT1,
                                               const float* __restrict__ b_h1,
                                               float* __restrict__ Xp) {
    const int lane = threadIdx.x & 63;
    const int wv   = threadIdx.x >> 6;
    const int bt   = blockIdx.x * 4 + wv;   // grid = T*B/4 = 16000
    const int b    = bt & (BB - 1);
    const int t    = bt >> 8;

    __shared__ __align__(16) int lst[4][712];

    const float* xrow = x + ((size_t)b * TT + t) * DIN;
    int cnt = 0;
    for (int c = 0; c < 11; ++c) {
        int d = c * 64 + lane;
        bool p = false;
        if (d < DIN) p = (__builtin_nontemporal_load(xrow + d) != 0.0f);
        unsigned long long m = __ballot(p ? 1 : 0);
        if (p) {
            int pos = cnt + __popcll(m & ((1ull << lane) - 1ull));
            lst[wv][pos] = d;
        }
        cnt += __popcll(m);
    }
    int cntp = (cnt + 7) & ~7;
    if (lane < cntp - cnt) lst[wv][cnt + lane] = DIN;   // zero row pad
    __syncthreads();

    f32x4 acc0 = *(const f32x4*)(b_h1 + lane * 4);
    f32x4 acc1 = {0.f, 0.f, 0.f, 0.f};
    const int lo = lane * 4;
    for (int k = 0; k < cntp; k += 8) {
        int4 ja = *(const int4*)&lst[wv][k];
        int4 jb = *(const int4*)&lst[wv][k + 4];
        f32x4 w0 = *(const f32x4*)(wT1 + ((size_t)ja.x << 8) + lo);
        f32x4 w1 = *(const f32x4*)(wT1 + ((size_t)ja.y << 8) + lo);
        f32x4 w2 = *(const f32x4*)(wT1 + ((size_t)ja.z << 8) + lo);
        f32x4 w3 = *(const f32x4*)(wT1 + ((size_t)ja.w << 8) + lo);
        f32x4 w4 = *(const f32x4*)(wT1 + ((size_t)jb.x << 8) + lo);
        f32x4 w5 = *(const f32x4*)(wT1 + ((size_t)jb.y << 8) + lo);
        f32x4 w6 = *(const f32x4*)(wT1 + ((size_t)jb.z << 8) + lo);
        f32x4 w7 = *(const f32x4*)(wT1 + ((size_t)jb.w << 8) + lo);
        acc0 += (w0 + w1) + (w2 + w3);
        acc1 += (w4 + w5) + (w6 + w7);
    }
    acc0 += acc1;
    __builtin_nontemporal_store(acc0, (f32x4*)(Xp + ((size_t)t * BB + b) * H1 + lo));
}

// issue 16 gathered loads from rows L[g..g+16) of a 256-stride table, col h
__device__ __forceinline__ void load16(const float* __restrict__ W,
                                       const int* __restrict__ L, int g, int h,
                                       float* __restrict__ v) {
    #pragma unroll
    for (int i = 0; i < 16; i += 4) {
        int4 a = *(const int4*)(L + g + i);
        v[i + 0] = W[((size_t)a.x << 8) + h];
        v[i + 1] = W[((size_t)a.y << 8) + h];
        v[i + 2] = W[((size_t)a.z << 8) + h];
        v[i + 3] = W[((size_t)a.w << 8) + h];
    }
}

// same for the stride-20 output table
__device__ __forceinline__ void load16o(const float* __restrict__ W,
                                        const int* __restrict__ L, int g, int h,
                                        float* __restrict__ v) {
    #pragma unroll
    for (int i = 0; i < 16; i += 4) {
        int4 a = *(const int4*)(L + g + i);
        v[i + 0] = W[a.x * DOUT + h];
        v[i + 1] = W[a.y * DOUT + h];
        v[i + 2] = W[a.z * DOUT + h];
        v[i + 3] = W[a.w * DOUT + h];
    }
}

__device__ __forceinline__ float sum16(const float* __restrict__ v) {
    return (((v[0] + v[1]) + (v[2] + v[3])) + ((v[4] + v[5]) + (v[6] + v[7])))
         + (((v[8] + v[9]) + (v[10] + v[11])) + ((v[12] + v[13]) + (v[14] + v[15])));
}

// ---------------------------------------------------------------------------
// Recurrent loop: one 256-thread block per batch element, thread h = neuron.
// Both spike lists padded (zero-row dummies) to a COMMON 32-multiple length
// kmaxC at P4b -> P1 is a branch-free dual-stream gather, register
// double-buffered: group k+1's loads issue before group k's sums, so the
// vmcnt wait before each sum leaves the next group in flight.
// ---------------------------------------------------------------------------
__global__ __launch_bounds__(256) void rec_k(
    const float* __restrict__ Xp,
    const float* __restrict__ wT11, const float* __restrict__ wT12,
    const float* __restrict__ wT22, const float* __restrict__ wT2o,
    const float* __restrict__ b_h2, const float* __restrict__ b_o,
    const float* __restrict__ tau_adp_h1, const float* __restrict__ tau_adp_h2,
    const float* __restrict__ tau_m_h1, const float* __restrict__ tau_m_h2,
    const float* __restrict__ tau_m_o,
    float* __restrict__ out) {
    const int h    = threadIdx.x;
    const int lane = h & 63;
    const int wv   = h >> 6;
    const int b    = blockIdx.x;

    __shared__ __align__(16) int lst1[288];
    __shared__ __align__(16) int lst2[288];
    __shared__ unsigned long long wmask[4];
    __shared__ float smo[DOUT];

    const float alpha1 = expf(-1.0f / tau_m_h1[h]);
    const float ro1    = expf(-1.0f / tau_adp_h1[h]);
    const float alpha2 = expf(-1.0f / tau_m_h2[h]);
    const float ro2    = expf(-1.0f / tau_adp_h2[h]);
    const float bh2v   = b_h2[h];
    float alpo = 0.f, bov = 0.f;
    if (h < DOUT) { alpo = expf(-1.0f / tau_m_o[h]); bov = b_o[h]; }

    float mem1 = 0.f, spk1 = 0.f, bb1v = BJ0;
    float mem2 = 0.f, spk2 = 0.f, bb2v = BJ0;
    float memo = 0.f, accs = 0.f;
    int kmaxC = 0;   // common padded length for P1 (lst1 & lst2)
    int n1g   = 0;   // padded length of fresh lst1 for P3

    float xp_cur = __builtin_nontemporal_load(Xp + ((size_t)b) * H1 + h);  // t=0

    for (int t = 0; t < TT; ++t) {
        float xp_nxt = 0.f;
        if (t + 1 < TT)
            xp_nxt = __builtin_nontemporal_load(Xp + ((size_t)(t + 1) * BB + b) * H1 + h);

        // ---- P1: pipelined dual-stream gather (wT11/lst1, wT22/lst2, wT2o) ----
        float r1 = 0.f, r2 = 0.f, ro = 0.f;
        const bool doo = (h < DOUT) && (t > 0);
        if (kmaxC > 0) {
            float A0[16], B0[16], C0[16], A1[16], B1[16], C1[16];
            load16(wT11, lst1, 0, h, A0);
            load16(wT22, lst2, 0, h, B0);
            if (doo) load16o(wT2o, lst2, 0, h, C0);
            int g = 0;
            for (; g + 32 < kmaxC; g += 32) {
                load16(wT11, lst1, g + 16, h, A1);
                load16(wT22, lst2, g + 16, h, B1);
                if (doo) load16o(wT2o, lst2, g + 16, h, C1);
                r1 += sum16(A0); r2 += sum16(B0); if (doo) ro += sum16(C0);
                load16(wT11, lst1, g + 32, h, A0);
                load16(wT22, lst2, g + 32, h, B0);
                if (doo) load16o(wT2o, lst2, g + 32, h, C0);
                r1 += sum16(A1); r2 += sum16(B1); if (doo) ro += sum16(C1);
            }
            load16(wT11, lst1, g + 16, h, A1);
            load16(wT22, lst2, g + 16, h, B1);
            if (doo) load16o(wT2o, lst2, g + 16, h, C1);
            r1 += sum16(A0); r2 += sum16(B0); if (doo) ro += sum16(C0);
            r1 += sum16(A1); r2 += sum16(B1); if (doo) ro += sum16(C1);
        }

        // ---- U1: layer-1 update; output memo for step t-1 ----
        bb1v = ro1 * bb1v + BETAC * (1.f - ro1) * spk1;
        mem1 = mem1 * alpha1 - bb1v * spk1 + (1.f - alpha1) * (xp_cur + r1);
        float ns1 = (mem1 - bb1v - BJ0) > 0.f ? 1.f : 0.f;
        spk1 = ns1;
        unsigned long long m1 = __ballot(ns1 != 0.f ? 1 : 0);
        if (lane == 0) wmask[wv] = m1;
        if (doo) {
            memo = memo * alpo + (1.f - alpo) * (bov + ro);
            smo[h] = memo;
        }
        __syncthreads();                               // B1

        // ---- P2b: rebuild lst1 (pad to 32-mult); softmax accum for t-1 ----
        {
            int pos = __popcll(m1 & ((1ull << lane) - 1ull));
            int tot = 0;
            for (int w = 0; w < 4; ++w) {
                unsigned long long mw = wmask[w];
                if (w < wv) pos += __popcll(mw);
                tot += __popcll(mw);
            }
            if (ns1 != 0.f) lst1[pos] = h;
            int np = (tot + 31) & ~31;
            if (h < np - tot) lst1[tot + h] = DUMMY;
            n1g = np;
        }
        if (doo) {
            float mx = smo[0];
            for (int i = 1; i < DOUT; ++i) mx = fmaxf(mx, smo[i]);
            float s = 0.f;
            for (int i = 0; i < DOUT; ++i) s += expf(smo[i] - mx);
            accs += expf(memo - mx) / s;
        }
        __syncthreads();                               // B2

        // ---- P3: pipelined gather wT12 over fresh lst1 ----
        float r3 = 0.f;
        if (n1g > 0) {
            float D0[16], D1[16];
            load16(wT12, lst1, 0, h, D0);
            int g = 0;
            for (; g + 32 < n1g; g += 32) {
                load16(wT12, lst1, g + 16, h, D1);
                r3 += sum16(D0);
                load16(wT12, lst1, g + 32, h, D0);
                r3 += sum16(D1);
            }
            load16(wT12, lst1, g + 16, h, D1);
            r3 += sum16(D0);
            r3 += sum16(D1);
        }

        // ---- U2: layer-2 update ----
        bb2v = ro2 * bb2v + BETAC * (1.f - ro2) * spk2;
        mem2 = mem2 * alpha2 - bb2v * spk2 + (1.f - alpha2) * (bh2v + r2 + r3);
        float ns2 = (mem2 - bb2v - BJ0) > 0.f ? 1.f : 0.f;
        spk2 = ns2;
        unsigned long long m2 = __ballot(ns2 != 0.f ? 1 : 0);
        if (lane == 0) wmask[wv] = m2;
        __syncthreads();                               // B3

        // ---- P4b: rebuild lst2; pad BOTH lists to common kmaxC ----
        {
            int pos = __popcll(m2 & ((1ull << lane) - 1ull));
            int tot = 0;
            for (int w = 0; w < 4; ++w) {
                unsigned long long mw = wmask[w];
                if (w < wv) pos += __popcll(mw);
                tot += __popcll(mw);
            }
            if (ns2 != 0.f) lst2[pos] = h;
            int np2 = (tot + 31) & ~31;
            kmaxC = n1g > np2 ? n1g : np2;
            if (h < kmaxC - tot) lst2[tot + h] = DUMMY;   // pad lst2 to kmaxC
            if (h < kmaxC - n1g) lst1[n1g + h] = DUMMY;   // extend lst1 to kmaxC
        }
        __syncthreads();                               // B4

        xp_cur = xp_nxt;
    }

    // ---- Epilogue: output + softmax for final timestep ----
    if (h < DOUT) {
        float ro = 0.f;
        for (int g = 0; g < kmaxC; g += 16) {
            float C0[16];
            load16o(wT2o, lst2, g, h, C0);
            ro += sum16(C0);
        }
        memo = memo * alpo + (1.f - alpo) * (bov + ro);
        smo[h] = memo;
    }
    __syncthreads();
    if (h < DOUT) {
        float mx = smo[0];
        for (int i = 1; i < DOUT; ++i) mx = fmaxf(mx, smo[i]);
        float s = 0.f;
        for (int i = 0; i < DOUT; ++i) s += expf(smo[i] - mx);
        accs += expf(memo - mx) / s;
        out[b * DOUT + h] = accs;
    }
}

extern "C" void kernel_launch(void* const* d_in, const int* in_sizes, int n_in,
                              void* d_out, int out_size, void* d_ws, size_t ws_size,
                              hipStream_t stream) {
    const float* x          = (const float*)d_in[0];
    const float* w_i2h1     = (const float*)d_in[1];
    const float* w_h12h1    = (const float*)d_in[2];
    const float* w_h12h2    = (const float*)d_in[3];
    const float* w_h22h2    = (const float*)d_in[4];
    const float* w_h2o      = (const float*)d_in[5];
    const float* b_h1       = (const float*)d_in[6];
    const float* b_h2       = (const float*)d_in[7];
    const float* b_o        = (const float*)d_in[8];
    const float* tau_adp_h1 = (const float*)d_in[9];
    const float* tau_adp_h2 = (const float*)d_in[10];
    const float* tau_m_h1   = (const float*)d_in[11];
    const float* tau_m_h2   = (const float*)d_in[12];
    const float* tau_m_o    = (const float*)d_in[13];

    float* ws   = (float*)d_ws;
    float* wT1  = ws;
    float* wT11 = ws + OFF_WT11;
    float* wT12 = ws + OFF_WT12;
    float* wT22 = ws + OFF_WT22;
    float* wT2o = ws + OFF_WT2O;
    float* Xp   = ws + OFF_XP;

    transpose_all_k<<<(N_TRANS + 255) / 256, 256, 0, stream>>>(
        w_i2h1, w_h12h1, w_h12h2, w_h22h2, w_h2o, ws);

    xproj_k<<<(TT * BB) / 4, 256, 0, stream>>>(x, wT1, b_h1, Xp);

    rec_k<<<BB, 256, 0, stream>>>(Xp, wT11, wT12, wT22, wT2o,
                                  b_h2, b_o, tau_adp_h1, tau_adp_h2,
                                  tau_m_h1, tau_m_h2, tau_m_o,
                                  (float*)d_out);
}